// Round 1
// baseline (223.560 us; speedup 1.0000x reference)
//
#include <hip/hip_runtime.h>
#include <hip/hip_bf16.h>

// B=4, L=2048, D=1024, H=16, HD=64, K=32, MAXLEN=2048
#define LL 2048

typedef __bf16 bf16x8 __attribute__((ext_vector_type(8)));
typedef __bf16 bf16x4 __attribute__((ext_vector_type(4)));
typedef float f32x4 __attribute__((ext_vector_type(4)));

// async global->LDS, 16B per lane; LDS dest = wave-uniform base + lane*16
__device__ inline void gl_lds16(const __bf16* g, __bf16* l) {
    __builtin_amdgcn_global_load_lds((const __attribute__((address_space(1))) void*)g,
                                     (__attribute__((address_space(3))) void*)l, 16, 0, 0);
}

// ---------------------------------------------------------------------------
// Unified prep: blocks [0,4096) cast inputs_kv->A1; [4096,4608) cast r1->r1b;
// [4608,5120) transpose Wv; [5120,5632) transpose Wo; [5632,6144) transpose r2.
// ---------------------------------------------------------------------------
__global__ __launch_bounds__(256) void prep(const float* __restrict__ inputs_kv,
                                            const float* __restrict__ r1,
                                            const float* __restrict__ Wv,
                                            const float* __restrict__ Wo,
                                            const float* __restrict__ r2,
                                            __bf16* __restrict__ A1,
                                            __bf16* __restrict__ r1b,
                                            __bf16* __restrict__ Wvt,
                                            __bf16* __restrict__ Wot,
                                            __bf16* __restrict__ r2t) {
    __shared__ float Ls[32][65];
    int bid = blockIdx.x;
    const int tid = threadIdx.x;
    if (bid < 4608) {
        const float* in = (bid < 4096) ? inputs_kv : r1;
        __bf16* out = (bid < 4096) ? A1 : r1b;
        const int t = ((bid < 4096) ? bid : bid - 4096) * 256 + tid;
        const float4* in4 = (const float4*)in;
        float4 f0 = in4[t * 2], f1 = in4[t * 2 + 1];
        bf16x8 o;
        o[0] = (__bf16)f0.x; o[1] = (__bf16)f0.y; o[2] = (__bf16)f0.z; o[3] = (__bf16)f0.w;
        o[4] = (__bf16)f1.x; o[5] = (__bf16)f1.y; o[6] = (__bf16)f1.z; o[7] = (__bf16)f1.w;
        *(bf16x8*)&out[(size_t)t * 8] = o;
        return;
    }
    bid -= 4608;
    const float* in;
    __bf16* out;
    int R, C, r0, c0;
    if (bid < 512) {
        in = Wv; out = Wvt; R = 1024; C = 1024;
        c0 = (bid & 15) * 64; r0 = (bid >> 4) * 32;
    } else if (bid < 1024) {
        bid -= 512;
        in = Wo; out = Wot; R = 1024; C = 1024;
        c0 = (bid & 15) * 64; r0 = (bid >> 4) * 32;
    } else {
        bid -= 1024;
        const int bz = bid >> 5;
        in = r2 + (size_t)bz * 65536; out = r2t + (size_t)bz * 65536;
        R = 32; C = 2048;
        c0 = (bid & 31) * 64; r0 = 0;
    }
#pragma unroll
    for (int p = 0; p < 2; ++p) {
        int f = tid + 256 * p;
        int row = f >> 4, c4 = (f & 15) << 2;
        float4 v = *(const float4*)&in[(size_t)(r0 + row) * C + c0 + c4];
        Ls[row][c4 + 0] = v.x; Ls[row][c4 + 1] = v.y;
        Ls[row][c4 + 2] = v.z; Ls[row][c4 + 3] = v.w;
    }
    __syncthreads();
    const int orow = tid >> 2, rc = (tid & 3) << 3;
    bf16x8 o;
#pragma unroll
    for (int j = 0; j < 8; ++j) o[j] = (__bf16)Ls[rc + j][orow];
    *(bf16x8*)&out[(size_t)(c0 + orow) * R + r0 + rc] = o;
}

// ---------------------------------------------------------------------------
// bf16 MFMA GEMM (m97 recipe): C = A(MxK) @ Bt(NxK)^T + bias.
// MODE 0: scatter bf16 V into FRAGMENT-MAJOR layout V3:
//   tile(h, nc=n>>6, b) of 4096 elems at ((h*32+nc)*4+b)*4096;
//   within tile: frag(jt=hd>>4, ks=(n>>5)&1)*512 + (hd&15)*32 + ((n>>3)&3)*8 + (n&7)
//   -> every attn B-frag load is 64 lanes x 16B CONTIGUOUS (1KB).
// MODE 1: write fp32 C[row][col]
// ---------------------------------------------------------------------------
template <int MODE>
__global__ __launch_bounds__(256) void gemm_bt(const __bf16* __restrict__ A,
                                               const __bf16* __restrict__ Bt,
                                               const float* __restrict__ bias,
                                               void* __restrict__ Cout,
                                               int M, int N, int K) {
    __shared__ alignas(16) __bf16 As[128 * 32];
    __shared__ alignas(16) __bf16 Bs[128 * 32];
    const int tid = threadIdx.x;
    const int lane = tid & 63;
    const int wid = __builtin_amdgcn_readfirstlane(tid >> 6);
    const int row0 = blockIdx.y * 128, col0 = blockIdx.x * 128;
    const int l15 = lane & 15, quad = lane >> 4;
    const int wr = wid & 1, wc = wid >> 1;
    const int s0 = wid * 2, s1 = s0 + 1;

    const __bf16* ga0 = A + (size_t)(row0 + s0 * 16 + (lane >> 2)) * K + ((lane & 3) << 3);
    const __bf16* ga1 = ga0 + (size_t)16 * K;
    const __bf16* gb0 = Bt + (size_t)(col0 + s0 * 16 + (lane >> 2)) * K + ((lane & 3) << 3);
    const __bf16* gb1 = gb0 + (size_t)16 * K;
    __bf16* la0 = As + s0 * 512;
    __bf16* la1 = As + s1 * 512;
    __bf16* lb0 = Bs + s0 * 512;
    __bf16* lb1 = Bs + s1 * 512;

    f32x4 acc[4][4];
#pragma unroll
    for (int i = 0; i < 4; ++i)
#pragma unroll
        for (int j = 0; j < 4; ++j) acc[i][j] = (f32x4){0.f, 0.f, 0.f, 0.f};

    for (int k0 = 0; k0 < K; k0 += 32) {
        __syncthreads();
        gl_lds16(ga0 + k0, la0);
        gl_lds16(ga1 + k0, la1);
        gl_lds16(gb0 + k0, lb0);
        gl_lds16(gb1 + k0, lb1);
        __syncthreads();
        bf16x8 af[4], bfv[4];
#pragma unroll
        for (int i = 0; i < 4; ++i)
            af[i] = *(const bf16x8*)&As[(wr * 64 + i * 16 + l15) * 32 + quad * 8];
#pragma unroll
        for (int j = 0; j < 4; ++j)
            bfv[j] = *(const bf16x8*)&Bs[(wc * 64 + j * 16 + l15) * 32 + quad * 8];
#pragma unroll
        for (int i = 0; i < 4; ++i)
#pragma unroll
            for (int j = 0; j < 4; ++j)
                acc[i][j] = __builtin_amdgcn_mfma_f32_16x16x32_bf16(af[i], bfv[j], acc[i][j], 0, 0, 0);
    }

#pragma unroll
    for (int i = 0; i < 4; ++i) {
        const int rg = row0 + wr * 64 + i * 16 + quad * 4;  // rows rg..rg+3
#pragma unroll
        for (int j = 0; j < 4; ++j) {
            const int cg = col0 + wc * 64 + j * 16 + l15;
            const float bb = bias[cg];
            if (MODE == 0) {
                const int b = rg >> 11, n = rg & 2047;     // 4 consecutive n
                const int h = cg >> 6, hd = cg & 63;
                const int nc = n >> 6, ks = (n >> 5) & 1, qj = (n >> 3) & 3, j0 = n & 7;
                const int jt = hd >> 4, fl = hd & 15;
                __bf16* V3 = (__bf16*)Cout;
                bf16x4 v;
#pragma unroll
                for (int r = 0; r < 4; ++r) v[r] = (__bf16)(acc[i][j][r] + bb);
                *(bf16x4*)&V3[(size_t)(((h * 32 + nc) * 4 + b) * 4096) +
                              (jt * 2 + ks) * 512 + fl * 32 + qj * 8 + j0] = v;
            } else {
                float* Cf = (float*)Cout;
#pragma unroll
                for (int r = 0; r < 4; ++r)
                    Cf[(size_t)(rg + r) * N + cg] = acc[i][j][r] + bb;
            }
        }
    }
}

// ---------------------------------------------------------------------------
// attn v5: v4 + XOR-swizzled Ps (slot ^= (l15>>1)&3, both write and read).
// Unswizzled, a ds_read_b128 8-lane issue group (fixed quad, l15 varying with
// 64B row stride) hits only 2 bank-quads -> 4-way conflict; writes were 8-way.
// The row-XOR on the 16B slot index makes reads hit 8 distinct bank-quads per
// 8-lane group (conflict-free) and writes 2-way (free). Same bijection on both
// sides -> semantics unchanged.
// ---------------------------------------------------------------------------
__global__ __launch_bounds__(512) void attn_pv_v4(const __bf16* __restrict__ r1b,
                                                  const __bf16* __restrict__ r2t,
                                                  const __bf16* __restrict__ V3,
                                                  __bf16* __restrict__ yb) {
    __shared__ alignas(16) __bf16 Ps[2 * 2 * 4 * 1024];   // [buf][lh][i][ks*512+...] 32KB
    const int tid = threadIdx.x;
    const int lane = tid & 63;
    const int w = __builtin_amdgcn_readfirstlane(tid >> 6);
    const int b = w & 3, lh = w >> 2;
    const int l15 = lane & 15, quad = lane >> 4;
    const int id = blockIdx.x;
    const int h = id & 15;             // id%8 == h%8 -> per-XCD head locality
    const int l0 = (id >> 4) << 7;

    // r1 B-frags for this wave's 64 l (fixed)
    bf16x8 bf1[4];
#pragma unroll
    for (int i = 0; i < 4; ++i)
        bf1[i] = *(const bf16x8*)&r1b[(size_t)(h * 2048 + l0 + lh * 64 + i * 16 + l15) * 32 + quad * 8];

    const __bf16* r2p = r2t + (size_t)(h * 2048 + b * 16 + l15) * 32 + quad * 8;
    const __bf16* vp = V3 + (size_t)((h * 32) * 4 + b) * 4096 + l15 * 32 + quad * 8;

    // chunk-0 prefetch
    bf16x8 r2f = *(const bf16x8*)r2p;
    bf16x8 vpf[4][2];
#pragma unroll
    for (int jt = 0; jt < 4; ++jt)
#pragma unroll
        for (int ks = 0; ks < 2; ++ks)
            vpf[jt][ks] = *(const bf16x8*)(vp + (jt * 2 + ks) * 512);

    bf16x8 ones;
#pragma unroll
    for (int e = 0; e < 8; ++e) ones[e] = (__bf16)1.0f;

    f32x4 acc[4][4];
    f32x4 den[4];
#pragma unroll
    for (int i = 0; i < 4; ++i) {
        den[i] = (f32x4){0.f, 0.f, 0.f, 0.f};
#pragma unroll
        for (int j = 0; j < 4; ++j) acc[i][j] = (f32x4){0.f, 0.f, 0.f, 0.f};
    }
    const f32x4 zero4 = {0.f, 0.f, 0.f, 0.f};

    const int kw = b >> 1;                       // which ks this wave produces
    const int jg = (b & 1) * 2 + (quad >> 1);    // j-group within frag
    const int q4 = (quad & 1) * 4;
    const int swz = (l15 >> 1) & 3;              // bank swizzle for Ps slots

    for (int c = 0; c < 32; ++c) {
        const int cn = (c < 31) ? 1 : 0;         // last chunk: re-load (harmless)
        // scores S^T: rows = this wave's 16-n strip, cols = its 64 l
        f32x4 s[4];
#pragma unroll
        for (int i = 0; i < 4; ++i)
            s[i] = __builtin_amdgcn_mfma_f32_16x16x32_bf16(r2f, bf1[i], zero4, 0, 0, 0);
        r2f = *(const bf16x8*)(r2p + (size_t)cn * 2048);
        __bf16* ps = &Ps[((c & 1) * 2 + lh) * 4096];
#pragma unroll
        for (int i = 0; i < 4; ++i) {
            bf16x4 p4;
#pragma unroll
            for (int r = 0; r < 4; ++r) p4[r] = (__bf16)__expf(s[i][r]);
            *(bf16x4*)&ps[i * 1024 + kw * 512 + l15 * 32 + ((jg ^ swz) << 3) + q4] = p4;
        }
        __syncthreads();
        bf16x8 pa[4][2];
#pragma unroll
        for (int i = 0; i < 4; ++i)
#pragma unroll
            for (int ks = 0; ks < 2; ++ks)
                pa[i][ks] = *(const bf16x8*)&ps[i * 1024 + ks * 512 + l15 * 32 + ((quad ^ swz) << 3)];
        // PV + denominators (consume vpf), then prefetch next chunk's V
#pragma unroll
        for (int ks = 0; ks < 2; ++ks) {
#pragma unroll
            for (int i = 0; i < 4; ++i) {
#pragma unroll
                for (int jt = 0; jt < 4; ++jt)
                    acc[i][jt] = __builtin_amdgcn_mfma_f32_16x16x32_bf16(pa[i][ks], vpf[jt][ks],
                                                                         acc[i][jt], 0, 0, 0);
                den[i] = __builtin_amdgcn_mfma_f32_16x16x32_bf16(pa[i][ks], ones, den[i], 0, 0, 0);
            }
        }
        vp += cn * 16384;
#pragma unroll
        for (int jt = 0; jt < 4; ++jt)
#pragma unroll
            for (int ks = 0; ks < 2; ++ks)
                vpf[jt][ks] = *(const bf16x8*)(vp + (jt * 2 + ks) * 512);
    }

    // epilogue: den[i][r] is the softmax denom for l = lh*64+i*16+quad*4+r (per-lane!)
#pragma unroll
    for (int i = 0; i < 4; ++i) {
#pragma unroll
        for (int r = 0; r < 4; ++r) {
            const float iv = 1.0f / den[i][r];
            const int l = l0 + lh * 64 + i * 16 + quad * 4 + r;
            const size_t rowbase = ((size_t)b * LL + l) * 1024 + h * 64;
#pragma unroll
            for (int jt = 0; jt < 4; ++jt)
                yb[rowbase + jt * 16 + l15] = (__bf16)(acc[i][jt][r] * iv);
        }
    }
}

extern "C" void kernel_launch(void* const* d_in, const int* in_sizes, int n_in,
                              void* d_out, int out_size, void* d_ws, size_t ws_size,
                              hipStream_t stream) {
    const float* inputs_kv = (const float*)d_in[1];
    const float* Wv = (const float*)d_in[2];   // (D, H*HD)
    const float* bv = (const float*)d_in[3];   // (H*HD)
    const float* r1 = (const float*)d_in[4];   // (H, L, K)
    const float* r2 = (const float*)d_in[5];   // (H, K, L)
    const float* Wo = (const float*)d_in[6];   // (H*HD, D)
    const float* bo = (const float*)d_in[7];   // (D)
    float* out = (float*)d_out;

    char* ws = (char*)d_ws;
    const size_t MB = 1024 * 1024;
    __bf16* A1  = (__bf16*)(ws);             // 16 MB  bf16(inputs_kv) [8192][1024]
    __bf16* Wvt = (__bf16*)(ws + 16 * MB);   //  2 MB  Wv^T
    __bf16* Wot = (__bf16*)(ws + 18 * MB);   //  2 MB  Wo^T
    __bf16* r1b = (__bf16*)(ws + 20 * MB);   //  2 MB  bf16(r1) [h][l][32]
    __bf16* r2t = (__bf16*)(ws + 22 * MB);   //  2 MB  r2^T per head [h][n][32]
    __bf16* V3  = (__bf16*)(ws + 24 * MB);   // 16 MB  V fragment-major (see gemm MODE 0)
    __bf16* yb  = (__bf16*)(ws + 40 * MB);   // 16 MB  y [b][l][h*64+hd]

    prep<<<6144, 256, 0, stream>>>(inputs_kv, r1, Wv, Wo, r2, A1, r1b, Wvt, Wot, r2t);
    gemm_bt<0><<<dim3(8, 64), 256, 0, stream>>>(A1, Wvt, bv, V3, 8192, 1024, 1024);
    attn_pv_v4<<<256, 512, 0, stream>>>(r1b, r2t, V3, yb);
    gemm_bt<1><<<dim3(8, 64), 256, 0, stream>>>(yb, Wot, bo, out, 8192, 1024, 1024);
}

// Round 2
// 221.581 us; speedup vs baseline: 1.0089x; 1.0089x over previous
//
#include <hip/hip_runtime.h>
#include <hip/hip_bf16.h>

// B=4, L=2048, D=1024, H=16, HD=64, K=32, MAXLEN=2048
#define LL 2048

typedef __bf16 bf16x8 __attribute__((ext_vector_type(8)));
typedef __bf16 bf16x4 __attribute__((ext_vector_type(4)));
typedef float f32x4 __attribute__((ext_vector_type(4)));

// async global->LDS, 16B per lane; LDS dest = wave-uniform base + lane*16
__device__ inline void gl_lds16(const __bf16* g, __bf16* l) {
    __builtin_amdgcn_global_load_lds((const __attribute__((address_space(1))) void*)g,
                                     (__attribute__((address_space(3))) void*)l, 16, 0, 0);
}

// ---------------------------------------------------------------------------
// Unified prep: blocks [0,4096) cast inputs_kv->A1; [4096,4608) cast r1->r1b;
// [4608,5120) transpose Wv; [5120,5632) transpose Wo; [5632,6144) transpose r2.
// ---------------------------------------------------------------------------
__global__ __launch_bounds__(256) void prep(const float* __restrict__ inputs_kv,
                                            const float* __restrict__ r1,
                                            const float* __restrict__ Wv,
                                            const float* __restrict__ Wo,
                                            const float* __restrict__ r2,
                                            __bf16* __restrict__ A1,
                                            __bf16* __restrict__ r1b,
                                            __bf16* __restrict__ Wvt,
                                            __bf16* __restrict__ Wot,
                                            __bf16* __restrict__ r2t) {
    __shared__ float Ls[32][65];
    int bid = blockIdx.x;
    const int tid = threadIdx.x;
    if (bid < 4608) {
        const float* in = (bid < 4096) ? inputs_kv : r1;
        __bf16* out = (bid < 4096) ? A1 : r1b;
        const int t = ((bid < 4096) ? bid : bid - 4096) * 256 + tid;
        const float4* in4 = (const float4*)in;
        float4 f0 = in4[t * 2], f1 = in4[t * 2 + 1];
        bf16x8 o;
        o[0] = (__bf16)f0.x; o[1] = (__bf16)f0.y; o[2] = (__bf16)f0.z; o[3] = (__bf16)f0.w;
        o[4] = (__bf16)f1.x; o[5] = (__bf16)f1.y; o[6] = (__bf16)f1.z; o[7] = (__bf16)f1.w;
        *(bf16x8*)&out[(size_t)t * 8] = o;
        return;
    }
    bid -= 4608;
    const float* in;
    __bf16* out;
    int R, C, r0, c0;
    if (bid < 512) {
        in = Wv; out = Wvt; R = 1024; C = 1024;
        c0 = (bid & 15) * 64; r0 = (bid >> 4) * 32;
    } else if (bid < 1024) {
        bid -= 512;
        in = Wo; out = Wot; R = 1024; C = 1024;
        c0 = (bid & 15) * 64; r0 = (bid >> 4) * 32;
    } else {
        bid -= 1024;
        const int bz = bid >> 5;
        in = r2 + (size_t)bz * 65536; out = r2t + (size_t)bz * 65536;
        R = 32; C = 2048;
        c0 = (bid & 31) * 64; r0 = 0;
    }
#pragma unroll
    for (int p = 0; p < 2; ++p) {
        int f = tid + 256 * p;
        int row = f >> 4, c4 = (f & 15) << 2;
        float4 v = *(const float4*)&in[(size_t)(r0 + row) * C + c0 + c4];
        Ls[row][c4 + 0] = v.x; Ls[row][c4 + 1] = v.y;
        Ls[row][c4 + 2] = v.z; Ls[row][c4 + 3] = v.w;
    }
    __syncthreads();
    const int orow = tid >> 2, rc = (tid & 3) << 3;
    bf16x8 o;
#pragma unroll
    for (int j = 0; j < 8; ++j) o[j] = (__bf16)Ls[rc + j][orow];
    *(bf16x8*)&out[(size_t)(c0 + orow) * R + r0 + rc] = o;
}

// ---------------------------------------------------------------------------
// bf16 MFMA GEMM (m97 recipe): C = A(MxK) @ Bt(NxK)^T + bias.
// XCD-chunked tile swizzle (T1): flat id f -> g=(f&7)*64+(f>>3), bijective on
// [0,512). XCD k (f%8==k heuristic) owns row-panels [8k,8k+8) x all 8 col
// tiles -> per-XCD working set = 2MB A-slice + 2MB B = 4MB = one L2.
// Without this, the 8 col-blocks of each row-panel spread across all XCDs and
// A (16MB) is re-fetched 8x from L3 (~256MB/gemm total traffic).
// MODE 0: scatter bf16 V into FRAGMENT-MAJOR layout V3 (see attn).
// MODE 1: write fp32 C[row][col]
// ---------------------------------------------------------------------------
template <int MODE>
__global__ __launch_bounds__(256) void gemm_bt(const __bf16* __restrict__ A,
                                               const __bf16* __restrict__ Bt,
                                               const float* __restrict__ bias,
                                               void* __restrict__ Cout,
                                               int M, int N, int K) {
    __shared__ alignas(16) __bf16 As[128 * 32];
    __shared__ alignas(16) __bf16 Bs[128 * 32];
    const int tid = threadIdx.x;
    const int lane = tid & 63;
    const int wid = __builtin_amdgcn_readfirstlane(tid >> 6);
    // XCD-chunked swizzle: grid is (8,64) -> 512 flat ids
    const int f = blockIdx.y * 8 + blockIdx.x;
    const int g = (f & 7) * 64 + (f >> 3);
    const int row0 = (g >> 3) * 128, col0 = (g & 7) * 128;
    const int l15 = lane & 15, quad = lane >> 4;
    const int wr = wid & 1, wc = wid >> 1;
    const int s0 = wid * 2, s1 = s0 + 1;

    const __bf16* ga0 = A + (size_t)(row0 + s0 * 16 + (lane >> 2)) * K + ((lane & 3) << 3);
    const __bf16* ga1 = ga0 + (size_t)16 * K;
    const __bf16* gb0 = Bt + (size_t)(col0 + s0 * 16 + (lane >> 2)) * K + ((lane & 3) << 3);
    const __bf16* gb1 = gb0 + (size_t)16 * K;
    __bf16* la0 = As + s0 * 512;
    __bf16* la1 = As + s1 * 512;
    __bf16* lb0 = Bs + s0 * 512;
    __bf16* lb1 = Bs + s1 * 512;

    f32x4 acc[4][4];
#pragma unroll
    for (int i = 0; i < 4; ++i)
#pragma unroll
        for (int j = 0; j < 4; ++j) acc[i][j] = (f32x4){0.f, 0.f, 0.f, 0.f};

    for (int k0 = 0; k0 < K; k0 += 32) {
        __syncthreads();
        gl_lds16(ga0 + k0, la0);
        gl_lds16(ga1 + k0, la1);
        gl_lds16(gb0 + k0, lb0);
        gl_lds16(gb1 + k0, lb1);
        __syncthreads();
        bf16x8 af[4], bfv[4];
#pragma unroll
        for (int i = 0; i < 4; ++i)
            af[i] = *(const bf16x8*)&As[(wr * 64 + i * 16 + l15) * 32 + quad * 8];
#pragma unroll
        for (int j = 0; j < 4; ++j)
            bfv[j] = *(const bf16x8*)&Bs[(wc * 64 + j * 16 + l15) * 32 + quad * 8];
#pragma unroll
        for (int i = 0; i < 4; ++i)
#pragma unroll
            for (int j = 0; j < 4; ++j)
                acc[i][j] = __builtin_amdgcn_mfma_f32_16x16x32_bf16(af[i], bfv[j], acc[i][j], 0, 0, 0);
    }

#pragma unroll
    for (int i = 0; i < 4; ++i) {
        const int rg = row0 + wr * 64 + i * 16 + quad * 4;  // rows rg..rg+3
#pragma unroll
        for (int j = 0; j < 4; ++j) {
            const int cg = col0 + wc * 64 + j * 16 + l15;
            const float bb = bias[cg];
            if (MODE == 0) {
                const int b = rg >> 11, n = rg & 2047;     // 4 consecutive n
                const int h = cg >> 6, hd = cg & 63;
                const int nc = n >> 6, ks = (n >> 5) & 1, qj = (n >> 3) & 3, j0 = n & 7;
                const int jt = hd >> 4, fl = hd & 15;
                __bf16* V3 = (__bf16*)Cout;
                bf16x4 v;
#pragma unroll
                for (int r = 0; r < 4; ++r) v[r] = (__bf16)(acc[i][j][r] + bb);
                *(bf16x4*)&V3[(size_t)(((h * 32 + nc) * 4 + b) * 4096) +
                              (jt * 2 + ks) * 512 + fl * 32 + qj * 8 + j0] = v;
            } else {
                float* Cf = (float*)Cout;
#pragma unroll
                for (int r = 0; r < 4; ++r)
                    Cf[(size_t)(rg + r) * N + cg] = acc[i][j][r] + bb;
            }
        }
    }
}

// ---------------------------------------------------------------------------
// attn v6: 256 threads, 4 waves (one per batch b), 64 l-rows per block.
// Grid 16h x 32 = 512 blocks = 2 blocks/CU -> TWO independent barrier
// domains per CU: while one block drains its exp->LDS->barrier phase, the
// other block's PV MFMAs keep the matrix pipe fed (v4/v5 had 1 block/CU, so
// every __syncthreads stalled the whole CU; MfmaUtil stuck at 36%).
// Ps is 16KB/block (2 x 8KB double buffer). XOR bank swizzle kept from v5.
// T5 setprio around the PV MFMA cluster (measured +4-7% on attn, m191).
// ---------------------------------------------------------------------------
__global__ __launch_bounds__(256) void attn_pv_v6(const __bf16* __restrict__ r1b,
                                                  const __bf16* __restrict__ r2t,
                                                  const __bf16* __restrict__ V3,
                                                  __bf16* __restrict__ yb) {
    __shared__ alignas(16) __bf16 Ps[2 * 4 * 1024];   // [buf][i][ks*512+...] 16KB
    const int tid = threadIdx.x;
    const int lane = tid & 63;
    const int w = __builtin_amdgcn_readfirstlane(tid >> 6);
    const int b = w;                   // wave = batch strip
    const int l15 = lane & 15, quad = lane >> 4;
    const int id = blockIdx.x;
    const int h = id & 15;             // id%8 == h%8 -> per-XCD head locality
    const int l0 = (id >> 4) << 6;     // 32 l-blocks of 64

    // r1 B-frags for this block's 64 l (fixed)
    bf16x8 bf1[4];
#pragma unroll
    for (int i = 0; i < 4; ++i)
        bf1[i] = *(const bf16x8*)&r1b[(size_t)(h * 2048 + l0 + i * 16 + l15) * 32 + quad * 8];

    const __bf16* r2p = r2t + (size_t)(h * 2048 + b * 16 + l15) * 32 + quad * 8;
    const __bf16* vp = V3 + (size_t)((h * 32) * 4 + b) * 4096 + l15 * 32 + quad * 8;

    // chunk-0 prefetch
    bf16x8 r2f = *(const bf16x8*)r2p;
    bf16x8 vpf[4][2];
#pragma unroll
    for (int jt = 0; jt < 4; ++jt)
#pragma unroll
        for (int ks = 0; ks < 2; ++ks)
            vpf[jt][ks] = *(const bf16x8*)(vp + (jt * 2 + ks) * 512);

    bf16x8 ones;
#pragma unroll
    for (int e = 0; e < 8; ++e) ones[e] = (__bf16)1.0f;

    f32x4 acc[4][4];
    f32x4 den[4];
#pragma unroll
    for (int i = 0; i < 4; ++i) {
        den[i] = (f32x4){0.f, 0.f, 0.f, 0.f};
#pragma unroll
        for (int j = 0; j < 4; ++j) acc[i][j] = (f32x4){0.f, 0.f, 0.f, 0.f};
    }
    const f32x4 zero4 = {0.f, 0.f, 0.f, 0.f};

    const int kw = b >> 1;                       // which ks this wave produces
    const int jg = (b & 1) * 2 + (quad >> 1);    // j-group within frag
    const int q4 = (quad & 1) * 4;
    const int swz = (l15 >> 1) & 3;              // bank swizzle for Ps slots

    for (int c = 0; c < 32; ++c) {
        const int cn = (c < 31) ? 1 : 0;         // last chunk: re-load (harmless)
        // scores S^T: rows = this wave's 16-n strip, cols = the block's 64 l
        f32x4 s[4];
#pragma unroll
        for (int i = 0; i < 4; ++i)
            s[i] = __builtin_amdgcn_mfma_f32_16x16x32_bf16(r2f, bf1[i], zero4, 0, 0, 0);
        r2f = *(const bf16x8*)(r2p + (size_t)cn * 2048);
        __bf16* ps = &Ps[(c & 1) * 4096];
#pragma unroll
        for (int i = 0; i < 4; ++i) {
            bf16x4 p4;
#pragma unroll
            for (int r = 0; r < 4; ++r) p4[r] = (__bf16)__expf(s[i][r]);
            *(bf16x4*)&ps[i * 1024 + kw * 512 + l15 * 32 + ((jg ^ swz) << 3) + q4] = p4;
        }
        __syncthreads();
        bf16x8 pa[4][2];
#pragma unroll
        for (int i = 0; i < 4; ++i)
#pragma unroll
            for (int ks = 0; ks < 2; ++ks)
                pa[i][ks] = *(const bf16x8*)&ps[i * 1024 + ks * 512 + l15 * 32 + ((quad ^ swz) << 3)];
        // PV + denominators (consume vpf), then prefetch next chunk's V
        __builtin_amdgcn_s_setprio(1);
#pragma unroll
        for (int ks = 0; ks < 2; ++ks) {
#pragma unroll
            for (int i = 0; i < 4; ++i) {
#pragma unroll
                for (int jt = 0; jt < 4; ++jt)
                    acc[i][jt] = __builtin_amdgcn_mfma_f32_16x16x32_bf16(pa[i][ks], vpf[jt][ks],
                                                                         acc[i][jt], 0, 0, 0);
                den[i] = __builtin_amdgcn_mfma_f32_16x16x32_bf16(pa[i][ks], ones, den[i], 0, 0, 0);
            }
        }
        __builtin_amdgcn_s_setprio(0);
        vp += cn * 16384;
#pragma unroll
        for (int jt = 0; jt < 4; ++jt)
#pragma unroll
            for (int ks = 0; ks < 2; ++ks)
                vpf[jt][ks] = *(const bf16x8*)(vp + (jt * 2 + ks) * 512);
    }

    // epilogue: den[i][r] is the softmax denom for l = l0+i*16+quad*4+r (per-lane!)
#pragma unroll
    for (int i = 0; i < 4; ++i) {
#pragma unroll
        for (int r = 0; r < 4; ++r) {
            const float iv = 1.0f / den[i][r];
            const int l = l0 + i * 16 + quad * 4 + r;
            const size_t rowbase = ((size_t)b * LL + l) * 1024 + h * 64;
#pragma unroll
            for (int jt = 0; jt < 4; ++jt)
                yb[rowbase + jt * 16 + l15] = (__bf16)(acc[i][jt][r] * iv);
        }
    }
}

extern "C" void kernel_launch(void* const* d_in, const int* in_sizes, int n_in,
                              void* d_out, int out_size, void* d_ws, size_t ws_size,
                              hipStream_t stream) {
    const float* inputs_kv = (const float*)d_in[1];
    const float* Wv = (const float*)d_in[2];   // (D, H*HD)
    const float* bv = (const float*)d_in[3];   // (H*HD)
    const float* r1 = (const float*)d_in[4];   // (H, L, K)
    const float* r2 = (const float*)d_in[5];   // (H, K, L)
    const float* Wo = (const float*)d_in[6];   // (H*HD, D)
    const float* bo = (const float*)d_in[7];   // (D)
    float* out = (float*)d_out;

    char* ws = (char*)d_ws;
    const size_t MB = 1024 * 1024;
    __bf16* A1  = (__bf16*)(ws);             // 16 MB  bf16(inputs_kv) [8192][1024]
    __bf16* Wvt = (__bf16*)(ws + 16 * MB);   //  2 MB  Wv^T
    __bf16* Wot = (__bf16*)(ws + 18 * MB);   //  2 MB  Wo^T
    __bf16* r1b = (__bf16*)(ws + 20 * MB);   //  2 MB  bf16(r1) [h][l][32]
    __bf16* r2t = (__bf16*)(ws + 22 * MB);   //  2 MB  r2^T per head [h][n][32]
    __bf16* V3  = (__bf16*)(ws + 24 * MB);   // 16 MB  V fragment-major (see gemm MODE 0)
    __bf16* yb  = (__bf16*)(ws + 40 * MB);   // 16 MB  y [b][l][h*64+hd]

    prep<<<6144, 256, 0, stream>>>(inputs_kv, r1, Wv, Wo, r2, A1, r1b, Wvt, Wot, r2t);
    gemm_bt<0><<<dim3(8, 64), 256, 0, stream>>>(A1, Wvt, bv, V3, 8192, 1024, 1024);
    attn_pv_v6<<<512, 256, 0, stream>>>(r1b, r2t, V3, yb);
    gemm_bt<1><<<dim3(8, 64), 256, 0, stream>>>(yb, Wot, bo, out, 8192, 1024, 1024);
}

// Round 3
// 212.889 us; speedup vs baseline: 1.0501x; 1.0408x over previous
//
#include <hip/hip_runtime.h>
#include <hip/hip_bf16.h>

// B=4, L=2048, D=1024, H=16, HD=64, K=32, MAXLEN=2048
#define LL 2048

typedef __bf16 bf16x8 __attribute__((ext_vector_type(8)));
typedef __bf16 bf16x4 __attribute__((ext_vector_type(4)));
typedef float f32x4 __attribute__((ext_vector_type(4)));

// async global->LDS, 16B per lane; LDS dest = wave-uniform base + lane*16
__device__ inline void gl_lds16(const __bf16* g, __bf16* l) {
    __builtin_amdgcn_global_load_lds((const __attribute__((address_space(1))) void*)g,
                                     (__attribute__((address_space(3))) void*)l, 16, 0, 0);
}

// ---------------------------------------------------------------------------
// Unified prep: blocks [0,4096) cast inputs_kv->A1; [4096,4608) cast r1->r1b;
// [4608,5120) transpose Wv; [5120,5632) transpose Wo; [5632,6144) transpose r2.
// ---------------------------------------------------------------------------
__global__ __launch_bounds__(256) void prep(const float* __restrict__ inputs_kv,
                                            const float* __restrict__ r1,
                                            const float* __restrict__ Wv,
                                            const float* __restrict__ Wo,
                                            const float* __restrict__ r2,
                                            __bf16* __restrict__ A1,
                                            __bf16* __restrict__ r1b,
                                            __bf16* __restrict__ Wvt,
                                            __bf16* __restrict__ Wot,
                                            __bf16* __restrict__ r2t) {
    __shared__ float Ls[32][65];
    int bid = blockIdx.x;
    const int tid = threadIdx.x;
    if (bid < 4608) {
        const float* in = (bid < 4096) ? inputs_kv : r1;
        __bf16* out = (bid < 4096) ? A1 : r1b;
        const int t = ((bid < 4096) ? bid : bid - 4096) * 256 + tid;
        const float4* in4 = (const float4*)in;
        float4 f0 = in4[t * 2], f1 = in4[t * 2 + 1];
        bf16x8 o;
        o[0] = (__bf16)f0.x; o[1] = (__bf16)f0.y; o[2] = (__bf16)f0.z; o[3] = (__bf16)f0.w;
        o[4] = (__bf16)f1.x; o[5] = (__bf16)f1.y; o[6] = (__bf16)f1.z; o[7] = (__bf16)f1.w;
        *(bf16x8*)&out[(size_t)t * 8] = o;
        return;
    }
    bid -= 4608;
    const float* in;
    __bf16* out;
    int R, C, r0, c0;
    if (bid < 512) {
        in = Wv; out = Wvt; R = 1024; C = 1024;
        c0 = (bid & 15) * 64; r0 = (bid >> 4) * 32;
    } else if (bid < 1024) {
        bid -= 512;
        in = Wo; out = Wot; R = 1024; C = 1024;
        c0 = (bid & 15) * 64; r0 = (bid >> 4) * 32;
    } else {
        bid -= 1024;
        const int bz = bid >> 5;
        in = r2 + (size_t)bz * 65536; out = r2t + (size_t)bz * 65536;
        R = 32; C = 2048;
        c0 = (bid & 31) * 64; r0 = 0;
    }
#pragma unroll
    for (int p = 0; p < 2; ++p) {
        int f = tid + 256 * p;
        int row = f >> 4, c4 = (f & 15) << 2;
        float4 v = *(const float4*)&in[(size_t)(r0 + row) * C + c0 + c4];
        Ls[row][c4 + 0] = v.x; Ls[row][c4 + 1] = v.y;
        Ls[row][c4 + 2] = v.z; Ls[row][c4 + 3] = v.w;
    }
    __syncthreads();
    const int orow = tid >> 2, rc = (tid & 3) << 3;
    bf16x8 o;
#pragma unroll
    for (int j = 0; j < 8; ++j) o[j] = (__bf16)Ls[rc + j][orow];
    *(bf16x8*)&out[(size_t)(c0 + orow) * R + r0 + rc] = o;
}

// ---------------------------------------------------------------------------
// bf16 MFMA GEMM (m97 recipe): C = A(MxK) @ Bt(NxK)^T + bias.
// XCD-chunked tile swizzle (T1): flat id f -> g=(f&7)*64+(f>>3), bijective on
// [0,512). Per-XCD working set = 2MB A-slice + 2MB B = 4MB = one L2.
// MODE 0: scatter bf16 V into FRAGMENT-MAJOR layout V3 (see attn).
// MODE 1: write fp32 C[row][col]
// ---------------------------------------------------------------------------
template <int MODE>
__global__ __launch_bounds__(256) void gemm_bt(const __bf16* __restrict__ A,
                                               const __bf16* __restrict__ Bt,
                                               const float* __restrict__ bias,
                                               void* __restrict__ Cout,
                                               int M, int N, int K) {
    __shared__ alignas(16) __bf16 As[128 * 32];
    __shared__ alignas(16) __bf16 Bs[128 * 32];
    const int tid = threadIdx.x;
    const int lane = tid & 63;
    const int wid = __builtin_amdgcn_readfirstlane(tid >> 6);
    // XCD-chunked swizzle: grid is (8,64) -> 512 flat ids
    const int f = blockIdx.y * 8 + blockIdx.x;
    const int g = (f & 7) * 64 + (f >> 3);
    const int row0 = (g >> 3) * 128, col0 = (g & 7) * 128;
    const int l15 = lane & 15, quad = lane >> 4;
    const int wr = wid & 1, wc = wid >> 1;
    const int s0 = wid * 2, s1 = s0 + 1;

    const __bf16* ga0 = A + (size_t)(row0 + s0 * 16 + (lane >> 2)) * K + ((lane & 3) << 3);
    const __bf16* ga1 = ga0 + (size_t)16 * K;
    const __bf16* gb0 = Bt + (size_t)(col0 + s0 * 16 + (lane >> 2)) * K + ((lane & 3) << 3);
    const __bf16* gb1 = gb0 + (size_t)16 * K;
    __bf16* la0 = As + s0 * 512;
    __bf16* la1 = As + s1 * 512;
    __bf16* lb0 = Bs + s0 * 512;
    __bf16* lb1 = Bs + s1 * 512;

    f32x4 acc[4][4];
#pragma unroll
    for (int i = 0; i < 4; ++i)
#pragma unroll
        for (int j = 0; j < 4; ++j) acc[i][j] = (f32x4){0.f, 0.f, 0.f, 0.f};

    for (int k0 = 0; k0 < K; k0 += 32) {
        __syncthreads();
        gl_lds16(ga0 + k0, la0);
        gl_lds16(ga1 + k0, la1);
        gl_lds16(gb0 + k0, lb0);
        gl_lds16(gb1 + k0, lb1);
        __syncthreads();
        bf16x8 af[4], bfv[4];
#pragma unroll
        for (int i = 0; i < 4; ++i)
            af[i] = *(const bf16x8*)&As[(wr * 64 + i * 16 + l15) * 32 + quad * 8];
#pragma unroll
        for (int j = 0; j < 4; ++j)
            bfv[j] = *(const bf16x8*)&Bs[(wc * 64 + j * 16 + l15) * 32 + quad * 8];
#pragma unroll
        for (int i = 0; i < 4; ++i)
#pragma unroll
            for (int j = 0; j < 4; ++j)
                acc[i][j] = __builtin_amdgcn_mfma_f32_16x16x32_bf16(af[i], bfv[j], acc[i][j], 0, 0, 0);
    }

#pragma unroll
    for (int i = 0; i < 4; ++i) {
        const int rg = row0 + wr * 64 + i * 16 + quad * 4;  // rows rg..rg+3
#pragma unroll
        for (int j = 0; j < 4; ++j) {
            const int cg = col0 + wc * 64 + j * 16 + l15;
            const float bb = bias[cg];
            if (MODE == 0) {
                const int b = rg >> 11, n = rg & 2047;     // 4 consecutive n
                const int h = cg >> 6, hd = cg & 63;
                const int nc = n >> 6, ks = (n >> 5) & 1, qj = (n >> 3) & 3, j0 = n & 7;
                const int jt = hd >> 4, fl = hd & 15;
                __bf16* V3 = (__bf16*)Cout;
                bf16x4 v;
#pragma unroll
                for (int r = 0; r < 4; ++r) v[r] = (__bf16)(acc[i][j][r] + bb);
                *(bf16x4*)&V3[(size_t)(((h * 32 + nc) * 4 + b) * 4096) +
                              (jt * 2 + ks) * 512 + fl * 32 + qj * 8 + j0] = v;
            } else {
                float* Cf = (float*)Cout;
#pragma unroll
                for (int r = 0; r < 4; ++r)
                    Cf[(size_t)(rg + r) * N + cg] = acc[i][j][r] + bb;
            }
        }
    }
}

// ---------------------------------------------------------------------------
// attn v7: v5 structure (512 thr, 8 waves, 1 block/CU, XOR-swizzled Ps)
// + chunk-level software pipeline. v5 was lockstep: QK(c)->exp(c)->barrier->
// PV(c); all waves ran exp (quarter-rate v_exp pipe, ~1000 cyc/chunk/CU) with
// the matrix pipe idle. v7 order per iteration:
//   lgkmcnt(0); s_barrier           (raw: vmcnt NOT drained -> V/r2 prefetch
//                                    stays in flight across barrier, T4)
//   pa <- Ps[c&1]                   (ds_read)
//   QK(c+1) MFMAs                   (indep of pa)
//   PV(c) MFMAs                     (40 MFMAs)
//   exp(c+1) + write Ps[(c+1)&1]    (VALU issues in PV MFMA shadow)
//   prefetch vpf(c+1), r2f(c+2)
// One barrier/iter is sufficient: reads of buf X in iter c complete before the
// wave's pre-barrier lgkm drain; writes of buf X in iter c+1 are after that
// barrier. Last-iteration QK/exp recompute chunk 31 into dead buf (harmless).
// ---------------------------------------------------------------------------
__global__ __launch_bounds__(512) void attn_pv_v7(const __bf16* __restrict__ r1b,
                                                  const __bf16* __restrict__ r2t,
                                                  const __bf16* __restrict__ V3,
                                                  __bf16* __restrict__ yb) {
    __shared__ alignas(16) __bf16 Ps[2 * 2 * 4 * 1024];   // [buf][lh][i][ks*512+...] 32KB
    const int tid = threadIdx.x;
    const int lane = tid & 63;
    const int w = __builtin_amdgcn_readfirstlane(tid >> 6);
    const int b = w & 3, lh = w >> 2;
    const int l15 = lane & 15, quad = lane >> 4;
    const int id = blockIdx.x;
    const int h = id & 15;             // id%8 == h%8 -> per-XCD head locality
    const int l0 = (id >> 4) << 7;

    // r1 B-frags for this wave's 64 l (fixed)
    bf16x8 bf1[4];
#pragma unroll
    for (int i = 0; i < 4; ++i)
        bf1[i] = *(const bf16x8*)&r1b[(size_t)(h * 2048 + l0 + lh * 64 + i * 16 + l15) * 32 + quad * 8];

    const __bf16* r2p = r2t + (size_t)(h * 2048 + b * 16 + l15) * 32 + quad * 8;
    const __bf16* vp = V3 + (size_t)((h * 32) * 4 + b) * 4096 + l15 * 32 + quad * 8;

    // chunk-0 prefetch
    bf16x8 r2f = *(const bf16x8*)r2p;
    bf16x8 vpf[4][2];
#pragma unroll
    for (int jt = 0; jt < 4; ++jt)
#pragma unroll
        for (int ks = 0; ks < 2; ++ks)
            vpf[jt][ks] = *(const bf16x8*)(vp + (jt * 2 + ks) * 512);

    bf16x8 ones;
#pragma unroll
    for (int e = 0; e < 8; ++e) ones[e] = (__bf16)1.0f;

    f32x4 acc[4][4];
    f32x4 den[4];
#pragma unroll
    for (int i = 0; i < 4; ++i) {
        den[i] = (f32x4){0.f, 0.f, 0.f, 0.f};
#pragma unroll
        for (int j = 0; j < 4; ++j) acc[i][j] = (f32x4){0.f, 0.f, 0.f, 0.f};
    }
    const f32x4 zero4 = {0.f, 0.f, 0.f, 0.f};

    const int kw = b >> 1;                       // which ks this wave produces
    const int jg = (b & 1) * 2 + (quad >> 1);    // j-group within frag
    const int q4 = (quad & 1) * 4;
    const int swz = (l15 >> 1) & 3;              // bank swizzle for Ps slots

    // ---- prologue: QK(0) -> exp -> write Ps[0]; prefetch r2f(1)
    f32x4 s[4];
#pragma unroll
    for (int i = 0; i < 4; ++i)
        s[i] = __builtin_amdgcn_mfma_f32_16x16x32_bf16(r2f, bf1[i], zero4, 0, 0, 0);
    r2f = *(const bf16x8*)(r2p + 2048);
    {
        __bf16* ps = &Ps[lh * 4096];
#pragma unroll
        for (int i = 0; i < 4; ++i) {
            bf16x4 p4;
#pragma unroll
            for (int r = 0; r < 4; ++r) p4[r] = (__bf16)__expf(s[i][r]);
            *(bf16x4*)&ps[i * 1024 + kw * 512 + l15 * 32 + ((jg ^ swz) << 3) + q4] = p4;
        }
    }

    for (int c = 0; c < 32; ++c) {
        asm volatile("s_waitcnt lgkmcnt(0)" ::: "memory");
        __builtin_amdgcn_s_barrier();
        const __bf16* ps_r = &Ps[((c & 1) * 2 + lh) * 4096];
        bf16x8 pa[4][2];
#pragma unroll
        for (int i = 0; i < 4; ++i)
#pragma unroll
            for (int ks = 0; ks < 2; ++ks)
                pa[i][ks] = *(const bf16x8*)&ps_r[i * 1024 + ks * 512 + l15 * 32 + ((quad ^ swz) << 3)];
        // QK(c+1): at c=31 this recomputes chunk 31 into a dead buffer
#pragma unroll
        for (int i = 0; i < 4; ++i)
            s[i] = __builtin_amdgcn_mfma_f32_16x16x32_bf16(r2f, bf1[i], zero4, 0, 0, 0);
        const int i2 = (c < 30) ? (c + 2) : 31;
        r2f = *(const bf16x8*)(r2p + (size_t)i2 * 2048);
        // PV(c) + denominators (consume pa, vpf)
#pragma unroll
        for (int ks = 0; ks < 2; ++ks) {
#pragma unroll
            for (int i = 0; i < 4; ++i) {
#pragma unroll
                for (int jt = 0; jt < 4; ++jt)
                    acc[i][jt] = __builtin_amdgcn_mfma_f32_16x16x32_bf16(pa[i][ks], vpf[jt][ks],
                                                                         acc[i][jt], 0, 0, 0);
                den[i] = __builtin_amdgcn_mfma_f32_16x16x32_bf16(pa[i][ks], ones, den[i], 0, 0, 0);
            }
        }
        // exp(c+1) + write Ps[(c+1)&1] — VALU, overlaps PV MFMA issue
        __bf16* ps_w = &Ps[(((c + 1) & 1) * 2 + lh) * 4096];
#pragma unroll
        for (int i = 0; i < 4; ++i) {
            bf16x4 p4;
#pragma unroll
            for (int r = 0; r < 4; ++r) p4[r] = (__bf16)__expf(s[i][r]);
            *(bf16x4*)&ps_w[i * 1024 + kw * 512 + l15 * 32 + ((jg ^ swz) << 3) + q4] = p4;
        }
        // V prefetch for chunk c+1 (stays in flight across next barrier)
        const int cv = (c < 31) ? 1 : 0;
        vp += cv * 16384;
#pragma unroll
        for (int jt = 0; jt < 4; ++jt)
#pragma unroll
            for (int ks = 0; ks < 2; ++ks)
                vpf[jt][ks] = *(const bf16x8*)(vp + (jt * 2 + ks) * 512);
    }

    // epilogue: den[i][r] is the softmax denom for l = lh*64+i*16+quad*4+r (per-lane!)
#pragma unroll
    for (int i = 0; i < 4; ++i) {
#pragma unroll
        for (int r = 0; r < 4; ++r) {
            const float iv = 1.0f / den[i][r];
            const int l = l0 + lh * 64 + i * 16 + quad * 4 + r;
            const size_t rowbase = ((size_t)b * LL + l) * 1024 + h * 64;
#pragma unroll
            for (int jt = 0; jt < 4; ++jt)
                yb[rowbase + jt * 16 + l15] = (__bf16)(acc[i][jt][r] * iv);
        }
    }
}

extern "C" void kernel_launch(void* const* d_in, const int* in_sizes, int n_in,
                              void* d_out, int out_size, void* d_ws, size_t ws_size,
                              hipStream_t stream) {
    const float* inputs_kv = (const float*)d_in[1];
    const float* Wv = (const float*)d_in[2];   // (D, H*HD)
    const float* bv = (const float*)d_in[3];   // (H*HD)
    const float* r1 = (const float*)d_in[4];   // (H, L, K)
    const float* r2 = (const float*)d_in[5];   // (H, K, L)
    const float* Wo = (const float*)d_in[6];   // (H*HD, D)
    const float* bo = (const float*)d_in[7];   // (D)
    float* out = (float*)d_out;

    char* ws = (char*)d_ws;
    const size_t MB = 1024 * 1024;
    __bf16* A1  = (__bf16*)(ws);             // 16 MB  bf16(inputs_kv) [8192][1024]
    __bf16* Wvt = (__bf16*)(ws + 16 * MB);   //  2 MB  Wv^T
    __bf16* Wot = (__bf16*)(ws + 18 * MB);   //  2 MB  Wo^T
    __bf16* r1b = (__bf16*)(ws + 20 * MB);   //  2 MB  bf16(r1) [h][l][32]
    __bf16* r2t = (__bf16*)(ws + 22 * MB);   //  2 MB  r2^T per head [h][n][32]
    __bf16* V3  = (__bf16*)(ws + 24 * MB);   // 16 MB  V fragment-major (see gemm MODE 0)
    __bf16* yb  = (__bf16*)(ws + 40 * MB);   // 16 MB  y [b][l][h*64+hd]

    prep<<<6144, 256, 0, stream>>>(inputs_kv, r1, Wv, Wo, r2, A1, r1b, Wvt, Wot, r2t);
    gemm_bt<0><<<dim3(8, 64), 256, 0, stream>>>(A1, Wvt, bv, V3, 8192, 1024, 1024);
    attn_pv_v7<<<256, 512, 0, stream>>>(r1b, r2t, V3, yb);
    gemm_bt<1><<<dim3(8, 64), 256, 0, stream>>>(yb, Wot, bo, out, 8192, 1024, 1024);
}